// Round 1
// baseline (637.684 us; speedup 1.0000x reference)
//
#include <hip/hip_runtime.h>
#include <hip/hip_bf16.h>

typedef unsigned short u16;
typedef short bf16x8 __attribute__((ext_vector_type(8)));
typedef float f32x4 __attribute__((ext_vector_type(4)));

__device__ __forceinline__ float b2f(u16 u) { return __uint_as_float(((unsigned)u) << 16); }
__device__ __forceinline__ u16 f2b(float f) {
    unsigned x = __float_as_uint(f);
    return (u16)((x + 0x7fffu + ((x >> 16) & 1u)) >> 16);
}

// ---------------- cast kernels ----------------
__global__ void cast_x_kernel(const float* __restrict__ x, u16* __restrict__ xb, int N, int Mpad) {
    size_t i4 = (size_t)blockIdx.x * blockDim.x + threadIdx.x;
    size_t total4 = (size_t)Mpad * 512 / 4;
    if (i4 >= total4) return;
    size_t base = i4 * 4;
    int row = (int)(base >> 9);
    ushort4 o;
    if (row < N) {
        float4 v = *(const float4*)(x + base);
        o = make_ushort4(f2b(v.x), f2b(v.y), f2b(v.z), f2b(v.w));
    } else {
        o = make_ushort4(0, 0, 0, 0);
    }
    *(ushort4*)(xb + base) = o;
}

__global__ void cast_wt_kernel(const float* __restrict__ W, u16* __restrict__ Wt) {
    int idx = blockIdx.x * blockDim.x + threadIdx.x;  // 512*512
    int n = idx >> 9, k = idx & 511;
    Wt[idx] = f2b(W[k * 512 + n]);
}

// ---------------- GEMM: h[M,512] = A[M,512] @ W[512,512], bf16 MFMA ----------------
// A row-major [Mpad,512] bf16; Bt = W^T row-major [512(N),512(K)] bf16; C row-major [Mpad,512] bf16.
__global__ __launch_bounds__(256, 2) void gemm_bf16(
    const u16* __restrict__ A, const u16* __restrict__ Bt, u16* __restrict__ C) {
    __shared__ u16 lA[128 * 32];
    __shared__ u16 lB[128 * 32];
    const int tid = threadIdx.x;
    const int w = tid >> 6, l = tid & 63;
    const int row0 = blockIdx.x * 128, col0 = blockIdx.y * 128;
    const int srow = (w << 4) + (l >> 2);  // 0..63 staging row within shot
    const int scol = (l & 3) << 3;         // k-chunk offset (8 elems = 16B)
    const int wr = w >> 1, wc = w & 1;
    const int mlane = l & 15, quad = l >> 4;

    f32x4 acc[4][4];
#pragma unroll
    for (int i = 0; i < 4; i++)
#pragma unroll
        for (int j = 0; j < 4; j++) acc[i][j] = f32x4{0.f, 0.f, 0.f, 0.f};

    for (int k0 = 0; k0 < 512; k0 += 32) {
#pragma unroll
        for (int s = 0; s < 2; ++s) {
            const u16* ga = A + (size_t)(row0 + s * 64 + srow) * 512 + (k0 + scol);
            const u16* gb = Bt + (size_t)(col0 + s * 64 + srow) * 512 + (k0 + scol);
            u16* la = lA + s * 2048 + w * 512;  // wave-uniform base; lane i lands at +16B*i
            u16* lb = lB + s * 2048 + w * 512;
            __builtin_amdgcn_global_load_lds((const __attribute__((address_space(1))) void*)ga,
                                             (__attribute__((address_space(3))) void*)la, 16, 0, 0);
            __builtin_amdgcn_global_load_lds((const __attribute__((address_space(1))) void*)gb,
                                             (__attribute__((address_space(3))) void*)lb, 16, 0, 0);
        }
        __syncthreads();  // compiler emits vmcnt(0) drain before barrier
        bf16x8 af[4], bfr[4];
#pragma unroll
        for (int i = 0; i < 4; i++) {
            af[i] = *(const bf16x8*)&lA[(wr * 64 + i * 16 + mlane) * 32 + quad * 8];
            bfr[i] = *(const bf16x8*)&lB[(wc * 64 + i * 16 + mlane) * 32 + quad * 8];
        }
#pragma unroll
        for (int i = 0; i < 4; i++)
#pragma unroll
            for (int j = 0; j < 4; j++)
                acc[i][j] = __builtin_amdgcn_mfma_f32_16x16x32_bf16(af[i], bfr[j], acc[i][j], 0, 0, 0);
        __syncthreads();
    }
#pragma unroll
    for (int i = 0; i < 4; i++)
#pragma unroll
        for (int j = 0; j < 4; j++)
#pragma unroll
            for (int r = 0; r < 4; r++) {
                int rg = row0 + wr * 64 + i * 16 + quad * 4 + r;  // C/D: row=quad*4+reg
                int cg = col0 + wc * 64 + j * 16 + mlane;         // col=lane&15
                C[(size_t)rg * 512 + cg] = f2b(acc[i][j][r]);
            }
}

// ---------------- per-node attention logits ----------------
__global__ __launch_bounds__(256) void att_scores(
    const u16* __restrict__ h, const float* __restrict__ att_src, const float* __restrict__ att_dst,
    float* __restrict__ asrc, float* __restrict__ adst, int N) {
    int node = blockIdx.x * 4 + (threadIdx.x >> 6);
    int lane = threadIdx.x & 63;
    if (node >= N) return;
    int head = lane >> 4, sub = lane & 15;
    bf16x8 hv = *(const bf16x8*)(h + (size_t)node * 512 + lane * 8);
    const float* as = att_src + head * 128 + sub * 8;
    const float* ad = att_dst + head * 128 + sub * 8;
    float ps = 0.f, pd = 0.f;
#pragma unroll
    for (int j = 0; j < 8; j++) {
        float hf = b2f((u16)hv[j]);
        ps += hf * as[j];
        pd += hf * ad[j];
    }
#pragma unroll
    for (int o = 8; o >= 1; o >>= 1) {
        ps += __shfl_xor(ps, o, 16);
        pd += __shfl_xor(pd, o, 16);
    }
    if (sub == 0) {
        asrc[node * 4 + head] = ps;
        adst[node * 4 + head] = pd;
    }
}

// ---------------- CSR build ----------------
__global__ void csr_count(const int* __restrict__ dst, int E, int* __restrict__ deg) {
    int i = blockIdx.x * blockDim.x + threadIdx.x;
    if (i < E) atomicAdd(&deg[dst[i]], 1);
}

__global__ void scan_kernel(const int* __restrict__ deg, int* __restrict__ off,
                            int* __restrict__ cursor, int n) {
    __shared__ int wsum[4];
    __shared__ int s_run;
    int tid = threadIdx.x, lane = tid & 63, wid = tid >> 6;
    if (tid == 0) s_run = 0;
    __syncthreads();
    int nchunk = (n + 255) / 256;
    for (int c = 0; c < nchunk; ++c) {
        int i = c * 256 + tid;
        int d = (i < n) ? deg[i] : 0;
        int x = d;
#pragma unroll
        for (int o = 1; o < 64; o <<= 1) {
            int y = __shfl_up(x, (unsigned)o, 64);
            if (lane >= o) x += y;
        }
        if (lane == 63) wsum[wid] = x;
        __syncthreads();
        int woff = 0;
        for (int j = 0; j < wid; ++j) woff += wsum[j];
        int run = s_run;
        int total = wsum[0] + wsum[1] + wsum[2] + wsum[3];
        int excl = run + woff + x - d;
        if (i < n) {
            off[i] = excl;
            cursor[i] = excl;
        }
        __syncthreads();
        if (tid == 0) s_run = run + total;
    }
    __syncthreads();
    if (tid == 0) off[n] = s_run;
}

__global__ void csr_scatter(const int* __restrict__ src, const int* __restrict__ dst, int E,
                            int* __restrict__ cursor, int* __restrict__ csrc) {
    int i = blockIdx.x * blockDim.x + threadIdx.x;
    if (i < E) {
        int p = atomicAdd(&cursor[dst[i]], 1);
        csrc[p] = src[i];
    }
}

// ---------------- per-dst online-softmax aggregation + leaky + mean-pool partials ----------------
__global__ __launch_bounds__(256) void gat_aggregate(
    const u16* __restrict__ h, const float* __restrict__ asrc, const float* __restrict__ adst,
    const int* __restrict__ off, const int* __restrict__ csrc, const float* __restrict__ bias,
    float* __restrict__ partial) {
    int dst = blockIdx.x;
    int w = threadIdx.x >> 6, l = threadIdx.x & 63;
    float ad = adst[dst * 4 + w];
    // self loop first
    float es = asrc[dst * 4 + w] + ad;
    es = es >= 0.f ? es : 0.2f * es;
    float m = es, lsum = 1.f;
    unsigned hb0 = *(const unsigned*)(h + (size_t)dst * 512 + w * 128 + l * 2);
    float acc0 = b2f((u16)(hb0 & 0xffff));
    float acc1 = b2f((u16)(hb0 >> 16));
    int p0 = off[dst], p1 = off[dst + 1];
    for (int p = p0; p < p1; ++p) {
        int s = csrc[p];
        float e = asrc[s * 4 + w] + ad;
        e = e >= 0.f ? e : 0.2f * e;
        float mn = fmaxf(m, e);
        float sc = __expf(m - mn);
        float wt = __expf(e - mn);
        unsigned hx = *(const unsigned*)(h + (size_t)s * 512 + w * 128 + l * 2);
        float g0 = b2f((u16)(hx & 0xffff));
        float g1 = b2f((u16)(hx >> 16));
        lsum = lsum * sc + wt;
        acc0 = acc0 * sc + wt * g0;
        acc1 = acc1 * sc + wt * g1;
        m = mn;
    }
    float inv = 1.f / (lsum + 1e-16f);
    int c = w * 128 + l * 2;
    float o0 = acc0 * inv + bias[c];
    float o1 = acc1 * inv + bias[c + 1];
    o0 = o0 >= 0.f ? o0 : 0.01f * o0;
    o1 = o1 >= 0.f ? o1 : 0.01f * o1;
    float* pp = partial + ((size_t)(dst & 511) * 512);
    atomicAdd(&pp[c], o0);
    atomicAdd(&pp[c + 1], o1);
}

// ---------------- reductions + fc ----------------
__global__ void reduce_partials(const float* __restrict__ pA, const float* __restrict__ pB,
                                float* __restrict__ g, float invN) {
    int idx = blockIdx.x * blockDim.x + threadIdx.x;  // 0..1023
    const float* p = (idx < 512) ? pA : pB;
    int c = idx & 511;
    float s = 0.f;
    for (int r = 0; r < 512; ++r) s += p[r * 512 + c];
    g[idx] = s * invN;
}

__global__ __launch_bounds__(256) void fc_final(
    const float* __restrict__ g, const float* __restrict__ w, const float* __restrict__ b,
    float* __restrict__ out) {
    __shared__ float gA[512], gB[512];
    int tid = threadIdx.x;
    for (int i = tid; i < 512; i += 256) {
        gA[i] = g[i];
        gB[i] = g[512 + i];
    }
    __syncthreads();
    int j = blockIdx.x * 256 + tid;
    float aA = b[j], aB = b[j];
    for (int k = 0; k < 512; ++k) {
        float wv = w[k * 512 + j];
        aA += gA[k] * wv;
        aB += gB[k] * wv;
    }
    aA = aA >= 0.f ? aA : 0.01f * aA;
    aB = aB >= 0.f ? aB : 0.01f * aB;
    out[j] = aA;
    out[512 + j] = aB;
    out[1024 + j] = aA - aB;
}

// ---------------- launch ----------------
extern "C" void kernel_launch(void* const* d_in, const int* in_sizes, int n_in,
                              void* d_out, int out_size, void* d_ws, size_t ws_size,
                              hipStream_t stream) {
    const float* x = (const float*)d_in[0];
    const int* adj = (const int*)d_in[1];
    const float* wtx = (const float*)d_in[2];
    const int* wadj = (const int*)d_in[3];
    const float* W = (const float*)d_in[4];
    const float* att_s = (const float*)d_in[5];
    const float* att_d = (const float*)d_in[6];
    const float* bias = (const float*)d_in[7];
    const float* fc1w = (const float*)d_in[8];
    const float* fc1b = (const float*)d_in[9];
    float* out = (float*)d_out;

    const int N = in_sizes[0] / 512;  // 20000
    const int E = in_sizes[1] / 2;    // 320000
    const int Mpad = ((N + 127) / 128) * 128;

    char* p = (char*)d_ws;
    auto alloc = [&](size_t bytes) -> char* {
        char* r = p;
        p += (bytes + 255) & ~(size_t)255;
        return r;
    };
    u16* xb = (u16*)alloc((size_t)Mpad * 512 * 2);
    u16* hb = (u16*)alloc((size_t)Mpad * 512 * 2);
    u16* Wt = (u16*)alloc(512 * 512 * 2);
    float* asrc = (float*)alloc((size_t)N * 4 * 4);
    float* adst = (float*)alloc((size_t)N * 4 * 4);
    int* deg = (int*)alloc((size_t)N * 4);
    int* off = (int*)alloc((size_t)(N + 1) * 4);
    int* cursor = (int*)alloc((size_t)N * 4);
    int* csrc = (int*)alloc((size_t)E * 4);
    float* partA = (float*)alloc(512 * 512 * 4);
    float* partB = (float*)alloc(512 * 512 * 4);
    float* gvec = (float*)alloc(1024 * 4);

    hipMemsetAsync(partA, 0, 512 * 512 * 4, stream);
    hipMemsetAsync(partB, 0, 512 * 512 * 4, stream);
    cast_wt_kernel<<<(512 * 512) / 256, 256, 0, stream>>>(W, Wt);

    for (int br = 0; br < 2; ++br) {
        const float* xcur = br ? wtx : x;
        const int* acur = br ? wadj : adj;
        float* pcur = br ? partB : partA;
        hipMemsetAsync(deg, 0, (size_t)N * 4, stream);
        size_t total4 = (size_t)Mpad * 512 / 4;
        cast_x_kernel<<<(int)((total4 + 255) / 256), 256, 0, stream>>>(xcur, xb, N, Mpad);
        dim3 gg(Mpad / 128, 4, 1);
        gemm_bf16<<<gg, 256, 0, stream>>>(xb, Wt, hb);
        att_scores<<<(N + 3) / 4, 256, 0, stream>>>(hb, att_s, att_d, asrc, adst, N);
        csr_count<<<(E + 255) / 256, 256, 0, stream>>>(acur + E, E, deg);
        scan_kernel<<<1, 256, 0, stream>>>(deg, off, cursor, N);
        csr_scatter<<<(E + 255) / 256, 256, 0, stream>>>(acur, acur + E, E, cursor, csrc);
        gat_aggregate<<<N, 256, 0, stream>>>(hb, asrc, adst, off, csrc, bias, pcur);
    }
    reduce_partials<<<4, 256, 0, stream>>>(partA, partB, gvec, 1.0f / (float)N);
    fc_final<<<2, 256, 0, stream>>>(gvec, fc1w, fc1b, out);
}

// Round 2
// 500.312 us; speedup vs baseline: 1.2746x; 1.2746x over previous
//
#include <hip/hip_runtime.h>
#include <hip/hip_bf16.h>

typedef unsigned short u16;
typedef short bf16x8 __attribute__((ext_vector_type(8)));
typedef float f32x4 __attribute__((ext_vector_type(4)));

__device__ __forceinline__ float b2f(u16 u) { return __uint_as_float(((unsigned)u) << 16); }
__device__ __forceinline__ u16 f2b(float f) {
    unsigned x = __float_as_uint(f);
    return (u16)((x + 0x7fffu + ((x >> 16) & 1u)) >> 16);
}

// ---------------- cast kernels ----------------
__global__ void cast_x_kernel(const float* __restrict__ x, u16* __restrict__ xb, int N, int Mpad) {
    size_t i4 = (size_t)blockIdx.x * blockDim.x + threadIdx.x;
    size_t total4 = (size_t)Mpad * 512 / 4;
    if (i4 >= total4) return;
    size_t base = i4 * 4;
    int row = (int)(base >> 9);
    ushort4 o;
    if (row < N) {
        float4 v = *(const float4*)(x + base);
        o = make_ushort4(f2b(v.x), f2b(v.y), f2b(v.z), f2b(v.w));
    } else {
        o = make_ushort4(0, 0, 0, 0);
    }
    *(ushort4*)(xb + base) = o;
}

__global__ void cast_wt_kernel(const float* __restrict__ W, u16* __restrict__ Wt) {
    int idx = blockIdx.x * blockDim.x + threadIdx.x;  // 512*512
    int n = idx >> 9, k = idx & 511;
    Wt[idx] = f2b(W[k * 512 + n]);
}

// ---------------- GEMM: h[M,512] = A[M,512] @ W[512,512], bf16 MFMA ----------------
__global__ __launch_bounds__(256, 2) void gemm_bf16(
    const u16* __restrict__ A, const u16* __restrict__ Bt, u16* __restrict__ C) {
    __shared__ u16 lA[128 * 32];
    __shared__ u16 lB[128 * 32];
    const int tid = threadIdx.x;
    const int w = tid >> 6, l = tid & 63;
    const int row0 = blockIdx.x * 128, col0 = blockIdx.y * 128;
    const int srow = (w << 4) + (l >> 2);
    const int scol = (l & 3) << 3;
    const int wr = w >> 1, wc = w & 1;
    const int mlane = l & 15, quad = l >> 4;

    f32x4 acc[4][4];
#pragma unroll
    for (int i = 0; i < 4; i++)
#pragma unroll
        for (int j = 0; j < 4; j++) acc[i][j] = f32x4{0.f, 0.f, 0.f, 0.f};

    for (int k0 = 0; k0 < 512; k0 += 32) {
#pragma unroll
        for (int s = 0; s < 2; ++s) {
            const u16* ga = A + (size_t)(row0 + s * 64 + srow) * 512 + (k0 + scol);
            const u16* gb = Bt + (size_t)(col0 + s * 64 + srow) * 512 + (k0 + scol);
            u16* la = lA + s * 2048 + w * 512;
            u16* lb = lB + s * 2048 + w * 512;
            __builtin_amdgcn_global_load_lds((const __attribute__((address_space(1))) void*)ga,
                                             (__attribute__((address_space(3))) void*)la, 16, 0, 0);
            __builtin_amdgcn_global_load_lds((const __attribute__((address_space(1))) void*)gb,
                                             (__attribute__((address_space(3))) void*)lb, 16, 0, 0);
        }
        __syncthreads();
        bf16x8 af[4], bfr[4];
#pragma unroll
        for (int i = 0; i < 4; i++) {
            af[i] = *(const bf16x8*)&lA[(wr * 64 + i * 16 + mlane) * 32 + quad * 8];
            bfr[i] = *(const bf16x8*)&lB[(wc * 64 + i * 16 + mlane) * 32 + quad * 8];
        }
#pragma unroll
        for (int i = 0; i < 4; i++)
#pragma unroll
            for (int j = 0; j < 4; j++)
                acc[i][j] = __builtin_amdgcn_mfma_f32_16x16x32_bf16(af[i], bfr[j], acc[i][j], 0, 0, 0);
        __syncthreads();
    }
#pragma unroll
    for (int i = 0; i < 4; i++)
#pragma unroll
        for (int j = 0; j < 4; j++)
#pragma unroll
            for (int r = 0; r < 4; r++) {
                int rg = row0 + wr * 64 + i * 16 + quad * 4 + r;
                int cg = col0 + wc * 64 + j * 16 + mlane;
                C[(size_t)rg * 512 + cg] = f2b(acc[i][j][r]);
            }
}

// ---------------- per-node attention logits ----------------
__global__ __launch_bounds__(256) void att_scores(
    const u16* __restrict__ h, const float* __restrict__ att_src, const float* __restrict__ att_dst,
    float* __restrict__ asrc, float* __restrict__ adst, int N) {
    int node = blockIdx.x * 4 + (threadIdx.x >> 6);
    int lane = threadIdx.x & 63;
    if (node >= N) return;
    int head = lane >> 4, sub = lane & 15;
    bf16x8 hv = *(const bf16x8*)(h + (size_t)node * 512 + lane * 8);
    const float* as = att_src + head * 128 + sub * 8;
    const float* ad = att_dst + head * 128 + sub * 8;
    float ps = 0.f, pd = 0.f;
#pragma unroll
    for (int j = 0; j < 8; j++) {
        float hf = b2f((u16)hv[j]);
        ps += hf * as[j];
        pd += hf * ad[j];
    }
#pragma unroll
    for (int o = 8; o >= 1; o >>= 1) {
        ps += __shfl_xor(ps, o, 16);
        pd += __shfl_xor(pd, o, 16);
    }
    if (sub == 0) {
        asrc[node * 4 + head] = ps;
        adst[node * 4 + head] = pd;
    }
}

// ---------------- CSR build (deg includes self-loop) ----------------
__global__ void init_deg(int* __restrict__ deg, int N) {
    int i = blockIdx.x * blockDim.x + threadIdx.x;
    if (i < N) deg[i] = 1;
}

__global__ void csr_count(const int* __restrict__ dst, int E, int* __restrict__ deg) {
    int i = blockIdx.x * blockDim.x + threadIdx.x;
    if (i < E) atomicAdd(&deg[dst[i]], 1);
}

// block-level exclusive scan (step A): per-block exclusive offsets + block sum
__global__ __launch_bounds__(256) void scanA(const int* __restrict__ deg, int* __restrict__ off,
                                             int* __restrict__ bsum, int n) {
    __shared__ int wsum[4];
    int tid = threadIdx.x, lane = tid & 63, wid = tid >> 6;
    int i = blockIdx.x * 256 + tid;
    int d = (i < n) ? deg[i] : 0;
    int x = d;
#pragma unroll
    for (int o = 1; o < 64; o <<= 1) {
        int y = __shfl_up(x, (unsigned)o, 64);
        if (lane >= o) x += y;
    }
    if (lane == 63) wsum[wid] = x;
    __syncthreads();
    int woff = 0;
    for (int j = 0; j < wid; ++j) woff += wsum[j];
    if (i < n) off[i] = woff + x - d;
    if (tid == 255) bsum[blockIdx.x] = woff + x;
}

// step B: scan block sums (nb <= 256), single block
__global__ __launch_bounds__(256) void scanB(const int* __restrict__ bsum, int* __restrict__ bbase,
                                             int nb, int* __restrict__ off, int n) {
    __shared__ int wsum[4];
    int tid = threadIdx.x, lane = tid & 63, wid = tid >> 6;
    int d = (tid < nb) ? bsum[tid] : 0;
    int x = d;
#pragma unroll
    for (int o = 1; o < 64; o <<= 1) {
        int y = __shfl_up(x, (unsigned)o, 64);
        if (lane >= o) x += y;
    }
    if (lane == 63) wsum[wid] = x;
    __syncthreads();
    int woff = 0;
    for (int j = 0; j < wid; ++j) woff += wsum[j];
    int excl = woff + x - d;
    if (tid < nb) bbase[tid] = excl;
    if (tid == nb - 1) off[n] = excl + d;
}

// step C: finalize offsets, place self-loop first, init cursor past it
__global__ void scanC(int* __restrict__ off, const int* __restrict__ bbase,
                      int* __restrict__ cursor, int* __restrict__ csrc, int n) {
    int i = blockIdx.x * blockDim.x + threadIdx.x;
    if (i < n) {
        int o = off[i] + bbase[i >> 8];
        off[i] = o;
        csrc[o] = i;  // self loop entry
        cursor[i] = o + 1;
    }
}

__global__ void csr_scatter(const int* __restrict__ src, const int* __restrict__ dst, int E,
                            int* __restrict__ cursor, int* __restrict__ csrc) {
    int i = blockIdx.x * blockDim.x + threadIdx.x;
    if (i < E) {
        int p = atomicAdd(&cursor[dst[i]], 1);
        csrc[p] = src[i];
    }
}

// ---------------- edge softmax: one wave per dst, 4 heads at once ----------------
__global__ __launch_bounds__(256) void compute_alpha(
    const float* __restrict__ asrc, const float* __restrict__ adst,
    const int* __restrict__ off, const int* __restrict__ csrc,
    float* __restrict__ alpha, int N) {
    int dst = blockIdx.x * 4 + (threadIdx.x >> 6);
    int lane = threadIdx.x & 63;
    if (dst >= N) return;
    int p0 = off[dst], p1 = off[dst + 1];
    float4 ad = *(const float4*)(adst + (size_t)dst * 4);
    float m0 = -1e30f, m1 = -1e30f, m2 = -1e30f, m3 = -1e30f;
    for (int p = p0 + lane; p < p1; p += 64) {
        int s = csrc[p];
        float4 as = *(const float4*)(asrc + (size_t)s * 4);
        float e0 = as.x + ad.x; e0 = e0 >= 0.f ? e0 : 0.2f * e0;
        float e1 = as.y + ad.y; e1 = e1 >= 0.f ? e1 : 0.2f * e1;
        float e2 = as.z + ad.z; e2 = e2 >= 0.f ? e2 : 0.2f * e2;
        float e3 = as.w + ad.w; e3 = e3 >= 0.f ? e3 : 0.2f * e3;
        m0 = fmaxf(m0, e0); m1 = fmaxf(m1, e1); m2 = fmaxf(m2, e2); m3 = fmaxf(m3, e3);
    }
#pragma unroll
    for (int o = 32; o >= 1; o >>= 1) {
        m0 = fmaxf(m0, __shfl_xor(m0, o));
        m1 = fmaxf(m1, __shfl_xor(m1, o));
        m2 = fmaxf(m2, __shfl_xor(m2, o));
        m3 = fmaxf(m3, __shfl_xor(m3, o));
    }
    float s0 = 0.f, s1 = 0.f, s2 = 0.f, s3 = 0.f;
    for (int p = p0 + lane; p < p1; p += 64) {
        int s = csrc[p];
        float4 as = *(const float4*)(asrc + (size_t)s * 4);
        float e0 = as.x + ad.x; e0 = e0 >= 0.f ? e0 : 0.2f * e0;
        float e1 = as.y + ad.y; e1 = e1 >= 0.f ? e1 : 0.2f * e1;
        float e2 = as.z + ad.z; e2 = e2 >= 0.f ? e2 : 0.2f * e2;
        float e3 = as.w + ad.w; e3 = e3 >= 0.f ? e3 : 0.2f * e3;
        s0 += __expf(e0 - m0); s1 += __expf(e1 - m1);
        s2 += __expf(e2 - m2); s3 += __expf(e3 - m3);
    }
#pragma unroll
    for (int o = 32; o >= 1; o >>= 1) {
        s0 += __shfl_xor(s0, o); s1 += __shfl_xor(s1, o);
        s2 += __shfl_xor(s2, o); s3 += __shfl_xor(s3, o);
    }
    float i0 = 1.f / (s0 + 1e-16f), i1 = 1.f / (s1 + 1e-16f);
    float i2 = 1.f / (s2 + 1e-16f), i3 = 1.f / (s3 + 1e-16f);
    for (int p = p0 + lane; p < p1; p += 64) {
        int s = csrc[p];
        float4 as = *(const float4*)(asrc + (size_t)s * 4);
        float e0 = as.x + ad.x; e0 = e0 >= 0.f ? e0 : 0.2f * e0;
        float e1 = as.y + ad.y; e1 = e1 >= 0.f ? e1 : 0.2f * e1;
        float e2 = as.z + ad.z; e2 = e2 >= 0.f ? e2 : 0.2f * e2;
        float e3 = as.w + ad.w; e3 = e3 >= 0.f ? e3 : 0.2f * e3;
        float4 av;
        av.x = __expf(e0 - m0) * i0; av.y = __expf(e1 - m1) * i1;
        av.z = __expf(e2 - m2) * i2; av.w = __expf(e3 - m3) * i3;
        *(float4*)(alpha + (size_t)p * 4) = av;
    }
}

// ---------------- weighted gather + bias + leaky + block-local mean-pool ----------------
__global__ __launch_bounds__(256) void gat_aggregate2(
    const u16* __restrict__ h, const int* __restrict__ off, const int* __restrict__ csrc,
    const float* __restrict__ alpha, const float* __restrict__ bias,
    float* __restrict__ partial, int N) {
    int w = threadIdx.x >> 6, l = threadIdx.x & 63;
    int c = w * 128 + l * 2;
    float b0 = bias[c], b1 = bias[c + 1];
    float pool0 = 0.f, pool1 = 0.f;
    for (int dst = blockIdx.x; dst < N; dst += gridDim.x) {
        int p0 = off[dst], p1 = off[dst + 1];
        float a0 = 0.f, a1 = 0.f;
        int s = csrc[p0];
        for (int p = p0; p < p1; ++p) {
            int sn = (p + 1 < p1) ? csrc[p + 1] : 0;
            float al = alpha[(size_t)p * 4 + w];
            unsigned hx = *(const unsigned*)(h + (size_t)s * 512 + c);
            a0 += al * b2f((u16)(hx & 0xffff));
            a1 += al * b2f((u16)(hx >> 16));
            s = sn;
        }
        float o0 = a0 + b0, o1 = a1 + b1;
        o0 = o0 >= 0.f ? o0 : 0.01f * o0;
        o1 = o1 >= 0.f ? o1 : 0.01f * o1;
        pool0 += o0;
        pool1 += o1;
    }
    float* pp = partial + (size_t)(blockIdx.x & 63) * 512;
    atomicAdd(&pp[c], pool0);
    atomicAdd(&pp[c + 1], pool1);
}

// ---------------- reductions + fc ----------------
__global__ void reduce_partials(const float* __restrict__ pA, const float* __restrict__ pB,
                                float* __restrict__ g, float invN) {
    int idx = blockIdx.x * blockDim.x + threadIdx.x;  // 0..1023
    const float* p = (idx < 512) ? pA : pB;
    int c = idx & 511;
    float s = 0.f;
    for (int r = 0; r < 64; ++r) s += p[r * 512 + c];
    g[idx] = s * invN;
}

__global__ __launch_bounds__(256) void fc_final(
    const float* __restrict__ g, const float* __restrict__ w, const float* __restrict__ b,
    float* __restrict__ out) {
    __shared__ float rA[256], rB[256];
    int t = threadIdx.x;
    int jj = t & 31, ks = t >> 5;
    int j = blockIdx.x * 32 + jj;
    float sA = 0.f, sB = 0.f;
    for (int k = ks * 64; k < ks * 64 + 64; ++k) {
        float wv = w[k * 512 + j];
        sA += g[k] * wv;
        sB += g[512 + k] * wv;
    }
    rA[t] = sA;
    rB[t] = sB;
    __syncthreads();
    if (ks == 0) {
#pragma unroll
        for (int s2 = 1; s2 < 8; ++s2) {
            sA += rA[jj + 32 * s2];
            sB += rB[jj + 32 * s2];
        }
        sA += b[j];
        sB += b[j];
        sA = sA >= 0.f ? sA : 0.01f * sA;
        sB = sB >= 0.f ? sB : 0.01f * sB;
        out[j] = sA;
        out[512 + j] = sB;
        out[1024 + j] = sA - sB;
    }
}

// ---------------- launch ----------------
extern "C" void kernel_launch(void* const* d_in, const int* in_sizes, int n_in,
                              void* d_out, int out_size, void* d_ws, size_t ws_size,
                              hipStream_t stream) {
    const float* x = (const float*)d_in[0];
    const int* adj = (const int*)d_in[1];
    const float* wtx = (const float*)d_in[2];
    const int* wadj = (const int*)d_in[3];
    const float* W = (const float*)d_in[4];
    const float* att_s = (const float*)d_in[5];
    const float* att_d = (const float*)d_in[6];
    const float* bias = (const float*)d_in[7];
    const float* fc1w = (const float*)d_in[8];
    const float* fc1b = (const float*)d_in[9];
    float* out = (float*)d_out;

    const int N = in_sizes[0] / 512;  // 20000
    const int E = in_sizes[1] / 2;    // 320000
    const int Mpad = ((N + 127) / 128) * 128;
    const int nb = (N + 255) / 256;  // scan blocks

    char* p = (char*)d_ws;
    auto alloc = [&](size_t bytes) -> char* {
        char* r = p;
        p += (bytes + 255) & ~(size_t)255;
        return r;
    };
    u16* xb = (u16*)alloc((size_t)Mpad * 512 * 2);
    u16* hb = (u16*)alloc((size_t)Mpad * 512 * 2);
    u16* Wt = (u16*)alloc(512 * 512 * 2);
    float* asrc = (float*)alloc((size_t)N * 4 * 4);
    float* adst = (float*)alloc((size_t)N * 4 * 4);
    int* deg = (int*)alloc((size_t)N * 4);
    int* off = (int*)alloc((size_t)(N + 1) * 4);
    int* cursor = (int*)alloc((size_t)N * 4);
    int* bsum = (int*)alloc(256 * 4);
    int* bbase = (int*)alloc(256 * 4);
    int* csrc = (int*)alloc((size_t)(E + N) * 4);
    float* alpha = (float*)alloc((size_t)(E + N) * 4 * 4);
    float* partA = (float*)alloc(64 * 512 * 4);
    float* partB = (float*)alloc(64 * 512 * 4);
    float* gvec = (float*)alloc(1024 * 4);

    hipMemsetAsync(partA, 0, 64 * 512 * 4, stream);
    hipMemsetAsync(partB, 0, 64 * 512 * 4, stream);
    cast_wt_kernel<<<(512 * 512) / 256, 256, 0, stream>>>(W, Wt);

    for (int br = 0; br < 2; ++br) {
        const float* xcur = br ? wtx : x;
        const int* acur = br ? wadj : adj;
        float* pcur = br ? partB : partA;
        init_deg<<<nb, 256, 0, stream>>>(deg, N);
        size_t total4 = (size_t)Mpad * 512 / 4;
        cast_x_kernel<<<(int)((total4 + 255) / 256), 256, 0, stream>>>(xcur, xb, N, Mpad);
        dim3 gg(Mpad / 128, 4, 1);
        gemm_bf16<<<gg, 256, 0, stream>>>(xb, Wt, hb);
        att_scores<<<(N + 3) / 4, 256, 0, stream>>>(hb, att_s, att_d, asrc, adst, N);
        csr_count<<<(E + 255) / 256, 256, 0, stream>>>(acur + E, E, deg);
        scanA<<<nb, 256, 0, stream>>>(deg, off, bsum, N);
        scanB<<<1, 256, 0, stream>>>(bsum, bbase, nb, off, N);
        scanC<<<nb, 256, 0, stream>>>(off, bbase, cursor, csrc, N);
        csr_scatter<<<(E + 255) / 256, 256, 0, stream>>>(acur, acur + E, E, cursor, csrc);
        compute_alpha<<<(N + 3) / 4, 256, 0, stream>>>(asrc, adst, off, csrc, alpha, N);
        gat_aggregate2<<<2048, 256, 0, stream>>>(hb, off, csrc, alpha, bias, pcur, N);
    }
    reduce_partials<<<4, 256, 0, stream>>>(partA, partB, gvec, 1.0f / (float)N);
    fc_final<<<16, 256, 0, stream>>>(gvec, fc1w, fc1b, out);
}

// Round 3
// 402.976 us; speedup vs baseline: 1.5824x; 1.2415x over previous
//
#include <hip/hip_runtime.h>
#include <hip/hip_bf16.h>

typedef unsigned short u16;
typedef short bf16x8 __attribute__((ext_vector_type(8)));
typedef float f32x4 __attribute__((ext_vector_type(4)));

__device__ __forceinline__ float b2f(u16 u) { return __uint_as_float(((unsigned)u) << 16); }
__device__ __forceinline__ u16 f2b(float f) {
    unsigned x = __float_as_uint(f);
    return (u16)((x + 0x7fffu + ((x >> 16) & 1u)) >> 16);
}

// ---------------- cast: both branches in one launch ----------------
// xb layout: [2*Mpad, 512] bf16; rows [0,N)=x, [Mpad,Mpad+N)=wt_x, pads zero.
__global__ void cast_x_all(const float* __restrict__ x, const float* __restrict__ wtx,
                           u16* __restrict__ xb, int N, int Mpad) {
    size_t i4 = (size_t)blockIdx.x * blockDim.x + threadIdx.x;
    size_t total4 = (size_t)2 * Mpad * 512 / 4;
    if (i4 >= total4) return;
    size_t base = i4 * 4;
    int prow = (int)(base >> 9);
    int br = prow >= Mpad;
    int lrow = prow - (br ? Mpad : 0);
    ushort4 o;
    if (lrow < N) {
        const float* src = br ? wtx : x;
        float4 v = *(const float4*)(src + (size_t)lrow * 512 + (base & 511));
        o = make_ushort4(f2b(v.x), f2b(v.y), f2b(v.z), f2b(v.w));
    } else {
        o = make_ushort4(0, 0, 0, 0);
    }
    *(ushort4*)(xb + base) = o;
}

__global__ void cast_wt_kernel(const float* __restrict__ W, u16* __restrict__ Wt) {
    int idx = blockIdx.x * blockDim.x + threadIdx.x;  // 512*512
    int n = idx >> 9, k = idx & 511;
    Wt[idx] = f2b(W[k * 512 + n]);
}

// ---------------- GEMM: h[M,512] = A[M,512] @ W[512,512], bf16 MFMA ----------------
__global__ __launch_bounds__(256, 2) void gemm_bf16(
    const u16* __restrict__ A, const u16* __restrict__ Bt, u16* __restrict__ C) {
    __shared__ u16 lA[128 * 32];
    __shared__ u16 lB[128 * 32];
    const int tid = threadIdx.x;
    const int w = tid >> 6, l = tid & 63;
    const int row0 = blockIdx.x * 128, col0 = blockIdx.y * 128;
    const int srow = (w << 4) + (l >> 2);
    const int scol = (l & 3) << 3;
    const int wr = w >> 1, wc = w & 1;
    const int mlane = l & 15, quad = l >> 4;

    f32x4 acc[4][4];
#pragma unroll
    for (int i = 0; i < 4; i++)
#pragma unroll
        for (int j = 0; j < 4; j++) acc[i][j] = f32x4{0.f, 0.f, 0.f, 0.f};

    for (int k0 = 0; k0 < 512; k0 += 32) {
#pragma unroll
        for (int s = 0; s < 2; ++s) {
            const u16* ga = A + (size_t)(row0 + s * 64 + srow) * 512 + (k0 + scol);
            const u16* gb = Bt + (size_t)(col0 + s * 64 + srow) * 512 + (k0 + scol);
            u16* la = lA + s * 2048 + w * 512;
            u16* lb = lB + s * 2048 + w * 512;
            __builtin_amdgcn_global_load_lds((const __attribute__((address_space(1))) void*)ga,
                                             (__attribute__((address_space(3))) void*)la, 16, 0, 0);
            __builtin_amdgcn_global_load_lds((const __attribute__((address_space(1))) void*)gb,
                                             (__attribute__((address_space(3))) void*)lb, 16, 0, 0);
        }
        __syncthreads();
        bf16x8 af[4], bfr[4];
#pragma unroll
        for (int i = 0; i < 4; i++) {
            af[i] = *(const bf16x8*)&lA[(wr * 64 + i * 16 + mlane) * 32 + quad * 8];
            bfr[i] = *(const bf16x8*)&lB[(wc * 64 + i * 16 + mlane) * 32 + quad * 8];
        }
#pragma unroll
        for (int i = 0; i < 4; i++)
#pragma unroll
            for (int j = 0; j < 4; j++)
                acc[i][j] = __builtin_amdgcn_mfma_f32_16x16x32_bf16(af[i], bfr[j], acc[i][j], 0, 0, 0);
        __syncthreads();
    }
#pragma unroll
    for (int i = 0; i < 4; i++)
#pragma unroll
        for (int j = 0; j < 4; j++)
#pragma unroll
            for (int r = 0; r < 4; r++) {
                int rg = row0 + wr * 64 + i * 16 + quad * 4 + r;
                int cg = col0 + wc * 64 + j * 16 + mlane;
                C[(size_t)rg * 512 + cg] = f2b(acc[i][j][r]);
            }
}

// ---------------- per-node attention logits, gid in [0,2N) ----------------
__global__ __launch_bounds__(256) void att_scores(
    const u16* __restrict__ h, const float* __restrict__ att_src, const float* __restrict__ att_dst,
    float* __restrict__ asrc, float* __restrict__ adst, int N, int Mpad) {
    int gid = blockIdx.x * 4 + (threadIdx.x >> 6);
    int lane = threadIdx.x & 63;
    if (gid >= 2 * N) return;
    int hrow = gid < N ? gid : gid - N + Mpad;
    int head = lane >> 4, sub = lane & 15;
    bf16x8 hv = *(const bf16x8*)(h + (size_t)hrow * 512 + lane * 8);
    const float* as = att_src + head * 128 + sub * 8;
    const float* ad = att_dst + head * 128 + sub * 8;
    float ps = 0.f, pd = 0.f;
#pragma unroll
    for (int j = 0; j < 8; j++) {
        float hf = b2f((u16)hv[j]);
        ps += hf * as[j];
        pd += hf * ad[j];
    }
#pragma unroll
    for (int o = 8; o >= 1; o >>= 1) {
        ps += __shfl_xor(ps, o, 16);
        pd += __shfl_xor(pd, o, 16);
    }
    if (sub == 0) {
        asrc[gid * 4 + head] = ps;
        adst[gid * 4 + head] = pd;
    }
}

// ---------------- CSR build over both graphs (2N nodes, 2E edges) ----------------
__global__ void init_deg(int* __restrict__ deg, int n2) {
    int i = blockIdx.x * blockDim.x + threadIdx.x;
    if (i < n2) deg[i] = 1;  // self loop
}

__global__ void csr_count(const int* __restrict__ adj, const int* __restrict__ wadj,
                          int E, int N, int* __restrict__ deg) {
    int i = blockIdx.x * blockDim.x + threadIdx.x;
    if (i < 2 * E) {
        int d = (i < E) ? adj[E + i] : (wadj[E + (i - E)] + N);
        atomicAdd(&deg[d], 1);
    }
}

__global__ __launch_bounds__(256) void scanA(const int* __restrict__ deg, int* __restrict__ off,
                                             int* __restrict__ bsum, int n) {
    __shared__ int wsum[4];
    int tid = threadIdx.x, lane = tid & 63, wid = tid >> 6;
    int i = blockIdx.x * 256 + tid;
    int d = (i < n) ? deg[i] : 0;
    int x = d;
#pragma unroll
    for (int o = 1; o < 64; o <<= 1) {
        int y = __shfl_up(x, (unsigned)o, 64);
        if (lane >= o) x += y;
    }
    if (lane == 63) wsum[wid] = x;
    __syncthreads();
    int woff = 0;
    for (int j = 0; j < wid; ++j) woff += wsum[j];
    if (i < n) off[i] = woff + x - d;
    if (tid == 255) bsum[blockIdx.x] = woff + x;
}

__global__ __launch_bounds__(256) void scanB(const int* __restrict__ bsum, int* __restrict__ bbase,
                                             int nb, int* __restrict__ off, int n) {
    __shared__ int wsum[4];
    int tid = threadIdx.x, lane = tid & 63, wid = tid >> 6;
    int d = (tid < nb) ? bsum[tid] : 0;
    int x = d;
#pragma unroll
    for (int o = 1; o < 64; o <<= 1) {
        int y = __shfl_up(x, (unsigned)o, 64);
        if (lane >= o) x += y;
    }
    if (lane == 63) wsum[wid] = x;
    __syncthreads();
    int woff = 0;
    for (int j = 0; j < wid; ++j) woff += wsum[j];
    int excl = woff + x - d;
    if (tid < nb) bbase[tid] = excl;
    if (tid == nb - 1) off[n] = excl + d;
}

__global__ void scanC(int* __restrict__ off, const int* __restrict__ bbase,
                      int* __restrict__ cursor, int* __restrict__ csrc, int n) {
    int i = blockIdx.x * blockDim.x + threadIdx.x;
    if (i < n) {
        int o = off[i] + bbase[i >> 8];
        off[i] = o;
        csrc[o] = i;  // self loop (gid)
        cursor[i] = o + 1;
    }
}

__global__ void csr_scatter(const int* __restrict__ adj, const int* __restrict__ wadj,
                            int E, int N, int* __restrict__ cursor, int* __restrict__ csrc) {
    int i = blockIdx.x * blockDim.x + threadIdx.x;
    if (i < 2 * E) {
        int s, d;
        if (i < E) {
            s = adj[i];
            d = adj[E + i];
        } else {
            s = wadj[i - E] + N;
            d = wadj[E + (i - E)] + N;
        }
        int p = atomicAdd(&cursor[d], 1);
        csrc[p] = s;
    }
}

// ---------------- edge softmax: 2 passes; store unnormalized exp, inv-denoms separate ----------------
__global__ __launch_bounds__(256) void compute_alpha(
    const float* __restrict__ asrc, const float* __restrict__ adst,
    const int* __restrict__ off, const int* __restrict__ csrc,
    float* __restrict__ alpha, float* __restrict__ dinv, int N2) {
    int dst = blockIdx.x * 4 + (threadIdx.x >> 6);
    int lane = threadIdx.x & 63;
    if (dst >= N2) return;
    int p0 = off[dst], p1 = off[dst + 1];
    float4 ad = *(const float4*)(adst + (size_t)dst * 4);
    float m0 = -1e30f, m1 = -1e30f, m2 = -1e30f, m3 = -1e30f;
    for (int p = p0 + lane; p < p1; p += 64) {
        int s = csrc[p];
        float4 as = *(const float4*)(asrc + (size_t)s * 4);
        float e0 = as.x + ad.x; e0 = e0 >= 0.f ? e0 : 0.2f * e0;
        float e1 = as.y + ad.y; e1 = e1 >= 0.f ? e1 : 0.2f * e1;
        float e2 = as.z + ad.z; e2 = e2 >= 0.f ? e2 : 0.2f * e2;
        float e3 = as.w + ad.w; e3 = e3 >= 0.f ? e3 : 0.2f * e3;
        *(float4*)(alpha + (size_t)p * 4) = make_float4(e0, e1, e2, e3);
        m0 = fmaxf(m0, e0); m1 = fmaxf(m1, e1); m2 = fmaxf(m2, e2); m3 = fmaxf(m3, e3);
    }
#pragma unroll
    for (int o = 32; o >= 1; o >>= 1) {
        m0 = fmaxf(m0, __shfl_xor(m0, o));
        m1 = fmaxf(m1, __shfl_xor(m1, o));
        m2 = fmaxf(m2, __shfl_xor(m2, o));
        m3 = fmaxf(m3, __shfl_xor(m3, o));
    }
    float s0 = 0.f, s1 = 0.f, s2 = 0.f, s3 = 0.f;
    for (int p = p0 + lane; p < p1; p += 64) {
        float4 e = *(const float4*)(alpha + (size_t)p * 4);
        float x0 = __expf(e.x - m0), x1 = __expf(e.y - m1);
        float x2 = __expf(e.z - m2), x3 = __expf(e.w - m3);
        *(float4*)(alpha + (size_t)p * 4) = make_float4(x0, x1, x2, x3);
        s0 += x0; s1 += x1; s2 += x2; s3 += x3;
    }
#pragma unroll
    for (int o = 32; o >= 1; o >>= 1) {
        s0 += __shfl_xor(s0, o); s1 += __shfl_xor(s1, o);
        s2 += __shfl_xor(s2, o); s3 += __shfl_xor(s3, o);
    }
    if (lane == 0) {
        *(float4*)(dinv + (size_t)dst * 4) =
            make_float4(1.f / (s0 + 1e-16f), 1.f / (s1 + 1e-16f),
                        1.f / (s2 + 1e-16f), 1.f / (s3 + 1e-16f));
    }
}

// ---------------- weighted gather, unroll-4 ILP, both branches ----------------
__global__ __launch_bounds__(256) void gat_aggregate2(
    const u16* __restrict__ h, const int* __restrict__ off, const int* __restrict__ csrc,
    const float* __restrict__ alpha, const float* __restrict__ dinv,
    const float* __restrict__ bias, float* __restrict__ partA, float* __restrict__ partB,
    int N, int Mpad) {
    int w = threadIdx.x >> 6, l = threadIdx.x & 63;
    int c = w * 128 + l * 2;
    float b0 = bias[c], b1 = bias[c + 1];
    float pA0 = 0.f, pA1 = 0.f, pB0 = 0.f, pB1 = 0.f;
    const int N2 = 2 * N;
    const int hoff = Mpad - N;  // add to gid>=N to get hrow
    for (int dst = blockIdx.x; dst < N2; dst += gridDim.x) {
        int p0 = off[dst], p1 = off[dst + 1];
        float x0 = 0.f, x1 = 0.f, y0 = 0.f, y1 = 0.f;
        float z0 = 0.f, z1 = 0.f, u0 = 0.f, u1 = 0.f;
        int p = p0;
        for (; p + 4 <= p1; p += 4) {
            int4 sv = *(const int4*)(csrc + p);
            int r0 = sv.x < N ? sv.x : sv.x + hoff;
            int r1 = sv.y < N ? sv.y : sv.y + hoff;
            int r2 = sv.z < N ? sv.z : sv.z + hoff;
            int r3 = sv.w < N ? sv.w : sv.w + hoff;
            float al0 = alpha[(size_t)p * 4 + w];
            float al1 = alpha[(size_t)(p + 1) * 4 + w];
            float al2 = alpha[(size_t)(p + 2) * 4 + w];
            float al3 = alpha[(size_t)(p + 3) * 4 + w];
            unsigned h0 = *(const unsigned*)(h + (size_t)r0 * 512 + c);
            unsigned h1 = *(const unsigned*)(h + (size_t)r1 * 512 + c);
            unsigned h2 = *(const unsigned*)(h + (size_t)r2 * 512 + c);
            unsigned h3 = *(const unsigned*)(h + (size_t)r3 * 512 + c);
            x0 += al0 * b2f((u16)(h0 & 0xffff)); x1 += al0 * b2f((u16)(h0 >> 16));
            y0 += al1 * b2f((u16)(h1 & 0xffff)); y1 += al1 * b2f((u16)(h1 >> 16));
            z0 += al2 * b2f((u16)(h2 & 0xffff)); z1 += al2 * b2f((u16)(h2 >> 16));
            u0 += al3 * b2f((u16)(h3 & 0xffff)); u1 += al3 * b2f((u16)(h3 >> 16));
        }
        for (; p < p1; ++p) {
            int s = csrc[p];
            int r = s < N ? s : s + hoff;
            float al = alpha[(size_t)p * 4 + w];
            unsigned hx = *(const unsigned*)(h + (size_t)r * 512 + c);
            x0 += al * b2f((u16)(hx & 0xffff));
            x1 += al * b2f((u16)(hx >> 16));
        }
        float inv = dinv[(size_t)dst * 4 + w];
        float o0 = (x0 + y0 + z0 + u0) * inv + b0;
        float o1 = (x1 + y1 + z1 + u1) * inv + b1;
        o0 = o0 >= 0.f ? o0 : 0.01f * o0;
        o1 = o1 >= 0.f ? o1 : 0.01f * o1;
        if (dst < N) {
            pA0 += o0; pA1 += o1;
        } else {
            pB0 += o0; pB1 += o1;
        }
    }
    float* ppA = partA + (size_t)(blockIdx.x & 63) * 512;
    float* ppB = partB + (size_t)(blockIdx.x & 63) * 512;
    atomicAdd(&ppA[c], pA0);
    atomicAdd(&ppA[c + 1], pA1);
    atomicAdd(&ppB[c], pB0);
    atomicAdd(&ppB[c + 1], pB1);
}

// ---------------- reductions + fc ----------------
__global__ void reduce_partials(const float* __restrict__ pA, const float* __restrict__ pB,
                                float* __restrict__ g, float invN) {
    int idx = blockIdx.x * blockDim.x + threadIdx.x;  // 0..1023
    const float* p = (idx < 512) ? pA : pB;
    int c = idx & 511;
    float s = 0.f;
    for (int r = 0; r < 64; ++r) s += p[r * 512 + c];
    g[idx] = s * invN;
}

__global__ __launch_bounds__(256) void fc_final(
    const float* __restrict__ g, const float* __restrict__ w, const float* __restrict__ b,
    float* __restrict__ out) {
    __shared__ float rA[256], rB[256];
    int t = threadIdx.x;
    int jj = t & 31, ks = t >> 5;
    int j = blockIdx.x * 32 + jj;
    float sA = 0.f, sB = 0.f;
    for (int k = ks * 64; k < ks * 64 + 64; ++k) {
        float wv = w[k * 512 + j];
        sA += g[k] * wv;
        sB += g[512 + k] * wv;
    }
    rA[t] = sA;
    rB[t] = sB;
    __syncthreads();
    if (ks == 0) {
#pragma unroll
        for (int s2 = 1; s2 < 8; ++s2) {
            sA += rA[jj + 32 * s2];
            sB += rB[jj + 32 * s2];
        }
        sA += b[j];
        sB += b[j];
        sA = sA >= 0.f ? sA : 0.01f * sA;
        sB = sB >= 0.f ? sB : 0.01f * sB;
        out[j] = sA;
        out[512 + j] = sB;
        out[1024 + j] = sA - sB;
    }
}

// ---------------- launch ----------------
extern "C" void kernel_launch(void* const* d_in, const int* in_sizes, int n_in,
                              void* d_out, int out_size, void* d_ws, size_t ws_size,
                              hipStream_t stream) {
    const float* x = (const float*)d_in[0];
    const int* adj = (const int*)d_in[1];
    const float* wtx = (const float*)d_in[2];
    const int* wadj = (const int*)d_in[3];
    const float* W = (const float*)d_in[4];
    const float* att_s = (const float*)d_in[5];
    const float* att_d = (const float*)d_in[6];
    const float* bias = (const float*)d_in[7];
    const float* fc1w = (const float*)d_in[8];
    const float* fc1b = (const float*)d_in[9];
    float* out = (float*)d_out;

    const int N = in_sizes[0] / 512;  // 20000
    const int E = in_sizes[1] / 2;    // 320000
    const int Mpad = ((N + 127) / 128) * 128;
    const int N2 = 2 * N;
    const int nb = (N2 + 255) / 256;  // scan blocks (157)

    char* p = (char*)d_ws;
    auto alloc = [&](size_t bytes) -> char* {
        char* r = p;
        p += (bytes + 255) & ~(size_t)255;
        return r;
    };
    u16* xb = (u16*)alloc((size_t)2 * Mpad * 512 * 2);
    u16* hb = (u16*)alloc((size_t)2 * Mpad * 512 * 2);
    u16* Wt = (u16*)alloc(512 * 512 * 2);
    float* asrc = (float*)alloc((size_t)N2 * 4 * 4);
    float* adst = (float*)alloc((size_t)N2 * 4 * 4);
    int* deg = (int*)alloc((size_t)N2 * 4);
    int* off = (int*)alloc((size_t)(N2 + 1) * 4);
    int* cursor = (int*)alloc((size_t)N2 * 4);
    int* bsum = (int*)alloc(256 * 4);
    int* bbase = (int*)alloc(256 * 4);
    int* csrc = (int*)alloc((size_t)2 * (E + N) * 4);
    float* alpha = (float*)alloc((size_t)2 * (E + N) * 4 * 4);
    float* dinv = (float*)alloc((size_t)N2 * 4 * 4);
    float* partA = (float*)alloc(64 * 512 * 4);
    float* partB = (float*)alloc(64 * 512 * 4);
    float* gvec = (float*)alloc(1024 * 4);

    hipMemsetAsync(partA, 0, 64 * 512 * 4, stream);
    hipMemsetAsync(partB, 0, 64 * 512 * 4, stream);
    cast_wt_kernel<<<(512 * 512) / 256, 256, 0, stream>>>(W, Wt);

    size_t total4 = (size_t)2 * Mpad * 512 / 4;
    cast_x_all<<<(int)((total4 + 255) / 256), 256, 0, stream>>>(x, wtx, xb, N, Mpad);

    // CSR build (independent of GEMM)
    init_deg<<<nb, 256, 0, stream>>>(deg, N2);
    csr_count<<<(2 * E + 255) / 256, 256, 0, stream>>>(adj, wadj, E, N, deg);
    scanA<<<nb, 256, 0, stream>>>(deg, off, bsum, N2);
    scanB<<<1, 256, 0, stream>>>(bsum, bbase, nb, off, N2);
    scanC<<<nb, 256, 0, stream>>>(off, bbase, cursor, csrc, N2);
    csr_scatter<<<(2 * E + 255) / 256, 256, 0, stream>>>(adj, wadj, E, N, cursor, csrc);

    // GEMM over both branches
    dim3 gg(2 * Mpad / 128, 4, 1);
    gemm_bf16<<<gg, 256, 0, stream>>>(xb, Wt, hb);
    att_scores<<<(N2 + 3) / 4, 256, 0, stream>>>(hb, att_s, att_d, asrc, adst, N, Mpad);

    compute_alpha<<<(N2 + 3) / 4, 256, 0, stream>>>(asrc, adst, off, csrc, alpha, dinv, N2);
    gat_aggregate2<<<2048, 256, 0, stream>>>(hb, off, csrc, alpha, dinv, bias, partA, partB,
                                             N, Mpad);

    reduce_partials<<<4, 256, 0, stream>>>(partA, partB, gvec, 1.0f / (float)N);
    fc_final<<<16, 256, 0, stream>>>(gvec, fc1w, fc1b, out);
}

// Round 4
// 387.646 us; speedup vs baseline: 1.6450x; 1.0395x over previous
//
#include <hip/hip_runtime.h>
#include <hip/hip_bf16.h>

typedef unsigned short u16;
typedef short bf16x8 __attribute__((ext_vector_type(8)));
typedef float f32x4 __attribute__((ext_vector_type(4)));

__device__ __forceinline__ float b2f(u16 u) { return __uint_as_float(((unsigned)u) << 16); }
__device__ __forceinline__ u16 f2b(float f) {
    unsigned x = __float_as_uint(f);
    return (u16)((x + 0x7fffu + ((x >> 16) & 1u)) >> 16);
}

// ---------------- cast: both branches in one launch ----------------
__global__ void cast_x_all(const float* __restrict__ x, const float* __restrict__ wtx,
                           u16* __restrict__ xb, int N, int Mpad) {
    size_t i4 = (size_t)blockIdx.x * blockDim.x + threadIdx.x;
    size_t total4 = (size_t)2 * Mpad * 512 / 4;
    if (i4 >= total4) return;
    size_t base = i4 * 4;
    int prow = (int)(base >> 9);
    int br = prow >= Mpad;
    int lrow = prow - (br ? Mpad : 0);
    ushort4 o;
    if (lrow < N) {
        const float* src = br ? wtx : x;
        float4 v = *(const float4*)(src + (size_t)lrow * 512 + (base & 511));
        o = make_ushort4(f2b(v.x), f2b(v.y), f2b(v.z), f2b(v.w));
    } else {
        o = make_ushort4(0, 0, 0, 0);
    }
    *(ushort4*)(xb + base) = o;
}

__global__ void cast_wt_kernel(const float* __restrict__ W, u16* __restrict__ Wt) {
    int idx = blockIdx.x * blockDim.x + threadIdx.x;  // 512*512
    int n = idx >> 9, k = idx & 511;
    Wt[idx] = f2b(W[k * 512 + n]);
}

// ---------------- GEMM: h[M,512] = A[M,512] @ W[512,512], bf16 MFMA ----------------
__global__ __launch_bounds__(256, 2) void gemm_bf16(
    const u16* __restrict__ A, const u16* __restrict__ Bt, u16* __restrict__ C) {
    __shared__ u16 lA[128 * 32];
    __shared__ u16 lB[128 * 32];
    const int tid = threadIdx.x;
    const int w = tid >> 6, l = tid & 63;
    const int row0 = blockIdx.x * 128, col0 = blockIdx.y * 128;
    const int srow = (w << 4) + (l >> 2);
    const int scol = (l & 3) << 3;
    const int wr = w >> 1, wc = w & 1;
    const int mlane = l & 15, quad = l >> 4;

    f32x4 acc[4][4];
#pragma unroll
    for (int i = 0; i < 4; i++)
#pragma unroll
        for (int j = 0; j < 4; j++) acc[i][j] = f32x4{0.f, 0.f, 0.f, 0.f};

    for (int k0 = 0; k0 < 512; k0 += 32) {
#pragma unroll
        for (int s = 0; s < 2; ++s) {
            const u16* ga = A + (size_t)(row0 + s * 64 + srow) * 512 + (k0 + scol);
            const u16* gb = Bt + (size_t)(col0 + s * 64 + srow) * 512 + (k0 + scol);
            u16* la = lA + s * 2048 + w * 512;
            u16* lb = lB + s * 2048 + w * 512;
            __builtin_amdgcn_global_load_lds((const __attribute__((address_space(1))) void*)ga,
                                             (__attribute__((address_space(3))) void*)la, 16, 0, 0);
            __builtin_amdgcn_global_load_lds((const __attribute__((address_space(1))) void*)gb,
                                             (__attribute__((address_space(3))) void*)lb, 16, 0, 0);
        }
        __syncthreads();
        bf16x8 af[4], bfr[4];
#pragma unroll
        for (int i = 0; i < 4; i++) {
            af[i] = *(const bf16x8*)&lA[(wr * 64 + i * 16 + mlane) * 32 + quad * 8];
            bfr[i] = *(const bf16x8*)&lB[(wc * 64 + i * 16 + mlane) * 32 + quad * 8];
        }
#pragma unroll
        for (int i = 0; i < 4; i++)
#pragma unroll
            for (int j = 0; j < 4; j++)
                acc[i][j] = __builtin_amdgcn_mfma_f32_16x16x32_bf16(af[i], bfr[j], acc[i][j], 0, 0, 0);
        __syncthreads();
    }
#pragma unroll
    for (int i = 0; i < 4; i++)
#pragma unroll
        for (int j = 0; j < 4; j++)
#pragma unroll
            for (int r = 0; r < 4; r++) {
                int rg = row0 + wr * 64 + i * 16 + quad * 4 + r;
                int cg = col0 + wc * 64 + j * 16 + mlane;
                C[(size_t)rg * 512 + cg] = f2b(acc[i][j][r]);
            }
}

// ---------------- attention logits + fp8 cast of h, gid in [0,2N) ----------------
__global__ __launch_bounds__(256) void att_scores_cast(
    const u16* __restrict__ h, const float* __restrict__ att_src, const float* __restrict__ att_dst,
    float* __restrict__ asrc, float* __restrict__ adst, unsigned char* __restrict__ h8,
    int N, int Mpad) {
    int gid = blockIdx.x * 4 + (threadIdx.x >> 6);
    int lane = threadIdx.x & 63;
    if (gid >= 2 * N) return;
    int hrow = gid < N ? gid : gid - N + Mpad;
    int head = lane >> 4, sub = lane & 15;
    bf16x8 hv = *(const bf16x8*)(h + (size_t)hrow * 512 + lane * 8);
    float hf[8];
#pragma unroll
    for (int j = 0; j < 8; j++) hf[j] = b2f((u16)hv[j]);

    // fp8 e4m3 pack (HW cvt, OCP on gfx950) and store 8 bytes
    int lo = __builtin_amdgcn_cvt_pk_fp8_f32(hf[0], hf[1], 0, false);
    lo = __builtin_amdgcn_cvt_pk_fp8_f32(hf[2], hf[3], lo, true);
    int hi = __builtin_amdgcn_cvt_pk_fp8_f32(hf[4], hf[5], 0, false);
    hi = __builtin_amdgcn_cvt_pk_fp8_f32(hf[6], hf[7], hi, true);
    *(int2*)(h8 + (size_t)hrow * 512 + lane * 8) = make_int2(lo, hi);

    const float* as = att_src + head * 128 + sub * 8;
    const float* ad = att_dst + head * 128 + sub * 8;
    float ps = 0.f, pd = 0.f;
#pragma unroll
    for (int j = 0; j < 8; j++) {
        ps += hf[j] * as[j];
        pd += hf[j] * ad[j];
    }
#pragma unroll
    for (int o = 8; o >= 1; o >>= 1) {
        ps += __shfl_xor(ps, o, 16);
        pd += __shfl_xor(pd, o, 16);
    }
    if (sub == 0) {
        asrc[gid * 4 + head] = ps;
        adst[gid * 4 + head] = pd;
    }
}

// ---------------- CSR build over both graphs (2N nodes, 2E edges) ----------------
__global__ void init_deg(int* __restrict__ deg, int n2) {
    int i = blockIdx.x * blockDim.x + threadIdx.x;
    if (i < n2) deg[i] = 1;  // self loop
}

__global__ void csr_count(const int* __restrict__ adj, const int* __restrict__ wadj,
                          int E, int N, int* __restrict__ deg) {
    int i = blockIdx.x * blockDim.x + threadIdx.x;
    if (i < 2 * E) {
        int d = (i < E) ? adj[E + i] : (wadj[E + (i - E)] + N);
        atomicAdd(&deg[d], 1);
    }
}

__global__ __launch_bounds__(256) void scanA(const int* __restrict__ deg, int* __restrict__ off,
                                             int* __restrict__ bsum, int n) {
    __shared__ int wsum[4];
    int tid = threadIdx.x, lane = tid & 63, wid = tid >> 6;
    int i = blockIdx.x * 256 + tid;
    int d = (i < n) ? deg[i] : 0;
    int x = d;
#pragma unroll
    for (int o = 1; o < 64; o <<= 1) {
        int y = __shfl_up(x, (unsigned)o, 64);
        if (lane >= o) x += y;
    }
    if (lane == 63) wsum[wid] = x;
    __syncthreads();
    int woff = 0;
    for (int j = 0; j < wid; ++j) woff += wsum[j];
    if (i < n) off[i] = woff + x - d;
    if (tid == 255) bsum[blockIdx.x] = woff + x;
}

__global__ __launch_bounds__(256) void scanB(const int* __restrict__ bsum, int* __restrict__ bbase,
                                             int nb, int* __restrict__ off, int n) {
    __shared__ int wsum[4];
    int tid = threadIdx.x, lane = tid & 63, wid = tid >> 6;
    int d = (tid < nb) ? bsum[tid] : 0;
    int x = d;
#pragma unroll
    for (int o = 1; o < 64; o <<= 1) {
        int y = __shfl_up(x, (unsigned)o, 64);
        if (lane >= o) x += y;
    }
    if (lane == 63) wsum[wid] = x;
    __syncthreads();
    int woff = 0;
    for (int j = 0; j < wid; ++j) woff += wsum[j];
    int excl = woff + x - d;
    if (tid < nb) bbase[tid] = excl;
    if (tid == nb - 1) off[n] = excl + d;
}

__global__ void scanC(int* __restrict__ off, const int* __restrict__ bbase,
                      int* __restrict__ cursor, int* __restrict__ csrc, int n) {
    int i = blockIdx.x * blockDim.x + threadIdx.x;
    if (i < n) {
        int o = off[i] + bbase[i >> 8];
        off[i] = o;
        csrc[o] = i;  // self loop (gid)
        cursor[i] = o + 1;
    }
}

__global__ void csr_scatter(const int* __restrict__ adj, const int* __restrict__ wadj,
                            int E, int N, int* __restrict__ cursor, int* __restrict__ csrc) {
    int i = blockIdx.x * blockDim.x + threadIdx.x;
    if (i < 2 * E) {
        int s, d;
        if (i < E) {
            s = adj[i];
            d = adj[E + i];
        } else {
            s = wadj[i - E] + N;
            d = wadj[E + (i - E)] + N;
        }
        int p = atomicAdd(&cursor[d], 1);
        csrc[p] = s;
    }
}

// ---------------- fused softmax + fp8 gather + pool ----------------
// Per dst: wave w = head w. Phase A: lanes=edges, compute m/denom, cache exp in sal[w][..]
// (wave-private LDS, no barriers). Phase B: lanes=channel-pairs, ILP-8 fp8 gather.
__global__ __launch_bounds__(256) void gat_aggregate3(
    const unsigned char* __restrict__ h8, const float* __restrict__ asrc,
    const float* __restrict__ adst, const int* __restrict__ off, const int* __restrict__ csrc,
    const float* __restrict__ bias, float* __restrict__ partA, float* __restrict__ partB,
    int N, int Mpad) {
    __shared__ float sal[4][256];
    int w = threadIdx.x >> 6, l = threadIdx.x & 63;
    int c = w * 128 + l * 2;
    float b0 = bias[c], b1 = bias[c + 1];
    float pA0 = 0.f, pA1 = 0.f, pB0 = 0.f, pB1 = 0.f;
    const int N2 = 2 * N;
    const int hoff = Mpad - N;
    for (int dst = blockIdx.x; dst < N2; dst += gridDim.x) {
        int p0 = off[dst], p1 = off[dst + 1];
        int deg = p1 - p0;
        float ad = adst[dst * 4 + w];
        // phase A: max
        float m = -1e30f;
        for (int p = p0 + l; p < p1; p += 64) {
            int s = csrc[p];
            float e = asrc[s * 4 + w] + ad;
            e = e >= 0.f ? e : 0.2f * e;
            m = fmaxf(m, e);
        }
#pragma unroll
        for (int o = 32; o >= 1; o >>= 1) m = fmaxf(m, __shfl_xor(m, o));
        // phase A: sum of exp, cache
        float ssum = 0.f;
        for (int p = p0 + l; p < p1; p += 64) {
            int s = csrc[p];
            float e = asrc[s * 4 + w] + ad;
            e = e >= 0.f ? e : 0.2f * e;
            float ex = __expf(e - m);
            ssum += ex;
            if (p - p0 < 256) sal[w][p - p0] = ex;
        }
#pragma unroll
        for (int o = 32; o >= 1; o >>= 1) ssum += __shfl_xor(ssum, o);
        float inv = 1.f / (ssum + 1e-16f);
        // phase B: gather, ILP-8
        float a0 = 0.f, a1 = 0.f, d0 = 0.f, d1 = 0.f;
        float e0 = 0.f, e1 = 0.f, f0 = 0.f, f1 = 0.f;
        int p = p0;
        int pend = p0 + (deg & ~7);
        for (; p < pend; p += 8) {
            int idx = p - p0;
            float4 alA, alB;
            if (idx + 8 <= 256) {
                alA = *(const float4*)&sal[w][idx];
                alB = *(const float4*)&sal[w][idx + 4];
            } else {
                float tmp[8];
#pragma unroll
                for (int k = 0; k < 8; ++k) {
                    int s2 = csrc[p + k];
                    float e = asrc[s2 * 4 + w] + ad;
                    e = e >= 0.f ? e : 0.2f * e;
                    tmp[k] = __expf(e - m);
                }
                alA = make_float4(tmp[0], tmp[1], tmp[2], tmp[3]);
                alB = make_float4(tmp[4], tmp[5], tmp[6], tmp[7]);
            }
            int4 sa = *(const int4*)(csrc + p);
            int4 sb = *(const int4*)(csrc + p + 4);
            int r0 = sa.x < N ? sa.x : sa.x + hoff;
            int r1 = sa.y < N ? sa.y : sa.y + hoff;
            int r2 = sa.z < N ? sa.z : sa.z + hoff;
            int r3 = sa.w < N ? sa.w : sa.w + hoff;
            int r4 = sb.x < N ? sb.x : sb.x + hoff;
            int r5 = sb.y < N ? sb.y : sb.y + hoff;
            int r6 = sb.z < N ? sb.z : sb.z + hoff;
            int r7 = sb.w < N ? sb.w : sb.w + hoff;
            unsigned v0 = *(const u16*)(h8 + (size_t)r0 * 512 + c);
            unsigned v1 = *(const u16*)(h8 + (size_t)r1 * 512 + c);
            unsigned v2 = *(const u16*)(h8 + (size_t)r2 * 512 + c);
            unsigned v3 = *(const u16*)(h8 + (size_t)r3 * 512 + c);
            unsigned v4 = *(const u16*)(h8 + (size_t)r4 * 512 + c);
            unsigned v5 = *(const u16*)(h8 + (size_t)r5 * 512 + c);
            unsigned v6 = *(const u16*)(h8 + (size_t)r6 * 512 + c);
            unsigned v7 = *(const u16*)(h8 + (size_t)r7 * 512 + c);
            a0 += alA.x * __builtin_amdgcn_cvt_f32_fp8(v0, 0);
            a1 += alA.x * __builtin_amdgcn_cvt_f32_fp8(v0, 1);
            d0 += alA.y * __builtin_amdgcn_cvt_f32_fp8(v1, 0);
            d1 += alA.y * __builtin_amdgcn_cvt_f32_fp8(v1, 1);
            e0 += alA.z * __builtin_amdgcn_cvt_f32_fp8(v2, 0);
            e1 += alA.z * __builtin_amdgcn_cvt_f32_fp8(v2, 1);
            f0 += alA.w * __builtin_amdgcn_cvt_f32_fp8(v3, 0);
            f1 += alA.w * __builtin_amdgcn_cvt_f32_fp8(v3, 1);
            a0 += alB.x * __builtin_amdgcn_cvt_f32_fp8(v4, 0);
            a1 += alB.x * __builtin_amdgcn_cvt_f32_fp8(v4, 1);
            d0 += alB.y * __builtin_amdgcn_cvt_f32_fp8(v5, 0);
            d1 += alB.y * __builtin_amdgcn_cvt_f32_fp8(v5, 1);
            e0 += alB.z * __builtin_amdgcn_cvt_f32_fp8(v6, 0);
            e1 += alB.z * __builtin_amdgcn_cvt_f32_fp8(v6, 1);
            f0 += alB.w * __builtin_amdgcn_cvt_f32_fp8(v7, 0);
            f1 += alB.w * __builtin_amdgcn_cvt_f32_fp8(v7, 1);
        }
        for (; p < p1; ++p) {
            int idx = p - p0;
            float al;
            if (idx < 256) {
                al = sal[w][idx];
            } else {
                int s2 = csrc[p];
                float e = asrc[s2 * 4 + w] + ad;
                e = e >= 0.f ? e : 0.2f * e;
                al = __expf(e - m);
            }
            int s = csrc[p];
            int r = s < N ? s : s + hoff;
            unsigned v = *(const u16*)(h8 + (size_t)r * 512 + c);
            a0 += al * __builtin_amdgcn_cvt_f32_fp8(v, 0);
            a1 += al * __builtin_amdgcn_cvt_f32_fp8(v, 1);
        }
        float o0 = (a0 + d0 + e0 + f0) * inv + b0;
        float o1 = (a1 + d1 + e1 + f1) * inv + b1;
        o0 = o0 >= 0.f ? o0 : 0.01f * o0;
        o1 = o1 >= 0.f ? o1 : 0.01f * o1;
        if (dst < N) {
            pA0 += o0; pA1 += o1;
        } else {
            pB0 += o0; pB1 += o1;
        }
    }
    float* ppA = partA + (size_t)(blockIdx.x & 63) * 512;
    float* ppB = partB + (size_t)(blockIdx.x & 63) * 512;
    atomicAdd(&ppA[c], pA0);
    atomicAdd(&ppA[c + 1], pA1);
    atomicAdd(&ppB[c], pB0);
    atomicAdd(&ppB[c + 1], pB1);
}

// ---------------- reductions + fc ----------------
__global__ void reduce_partials(const float* __restrict__ pA, const float* __restrict__ pB,
                                float* __restrict__ g, float invN) {
    int idx = blockIdx.x * blockDim.x + threadIdx.x;  // 0..1023
    const float* p = (idx < 512) ? pA : pB;
    int c = idx & 511;
    float s = 0.f;
    for (int r = 0; r < 64; ++r) s += p[r * 512 + c];
    g[idx] = s * invN;
}

__global__ __launch_bounds__(256) void fc_final(
    const float* __restrict__ g, const float* __restrict__ w, const float* __restrict__ b,
    float* __restrict__ out) {
    __shared__ float rA[256], rB[256];
    int t = threadIdx.x;
    int jj = t & 31, ks = t >> 5;
    int j = blockIdx.x * 32 + jj;
    float sA = 0.f, sB = 0.f;
    for (int k = ks * 64; k < ks * 64 + 64; ++k) {
        float wv = w[k * 512 + j];
        sA += g[k] * wv;
        sB += g[512 + k] * wv;
    }
    rA[t] = sA;
    rB[t] = sB;
    __syncthreads();
    if (ks == 0) {
#pragma unroll
        for (int s2 = 1; s2 < 8; ++s2) {
            sA += rA[jj + 32 * s2];
            sB += rB[jj + 32 * s2];
        }
        sA += b[j];
        sB += b[j];
        sA = sA >= 0.f ? sA : 0.01f * sA;
        sB = sB >= 0.f ? sB : 0.01f * sB;
        out[j] = sA;
        out[512 + j] = sB;
        out[1024 + j] = sA - sB;
    }
}

// ---------------- launch ----------------
extern "C" void kernel_launch(void* const* d_in, const int* in_sizes, int n_in,
                              void* d_out, int out_size, void* d_ws, size_t ws_size,
                              hipStream_t stream) {
    const float* x = (const float*)d_in[0];
    const int* adj = (const int*)d_in[1];
    const float* wtx = (const float*)d_in[2];
    const int* wadj = (const int*)d_in[3];
    const float* W = (const float*)d_in[4];
    const float* att_s = (const float*)d_in[5];
    const float* att_d = (const float*)d_in[6];
    const float* bias = (const float*)d_in[7];
    const float* fc1w = (const float*)d_in[8];
    const float* fc1b = (const float*)d_in[9];
    float* out = (float*)d_out;

    const int N = in_sizes[0] / 512;  // 20000
    const int E = in_sizes[1] / 2;    // 320000
    const int Mpad = ((N + 127) / 128) * 128;
    const int N2 = 2 * N;
    const int nb = (N2 + 255) / 256;

    char* p = (char*)d_ws;
    auto alloc = [&](size_t bytes) -> char* {
        char* r = p;
        p += (bytes + 255) & ~(size_t)255;
        return r;
    };
    u16* xb = (u16*)alloc((size_t)2 * Mpad * 512 * 2);
    u16* hb = (u16*)alloc((size_t)2 * Mpad * 512 * 2);
    unsigned char* h8 = (unsigned char*)alloc((size_t)2 * Mpad * 512);
    u16* Wt = (u16*)alloc(512 * 512 * 2);
    float* asrc = (float*)alloc((size_t)N2 * 4 * 4);
    float* adst = (float*)alloc((size_t)N2 * 4 * 4);
    int* deg = (int*)alloc((size_t)N2 * 4);
    int* off = (int*)alloc((size_t)(N2 + 1) * 4);
    int* cursor = (int*)alloc((size_t)N2 * 4);
    int* bsum = (int*)alloc(256 * 4);
    int* bbase = (int*)alloc(256 * 4);
    int* csrc = (int*)alloc((size_t)2 * (E + N) * 4);
    float* partA = (float*)alloc(64 * 512 * 4);
    float* partB = (float*)alloc(64 * 512 * 4);
    float* gvec = (float*)alloc(1024 * 4);

    hipMemsetAsync(partA, 0, 64 * 512 * 4, stream);
    hipMemsetAsync(partB, 0, 64 * 512 * 4, stream);
    cast_wt_kernel<<<(512 * 512) / 256, 256, 0, stream>>>(W, Wt);

    size_t total4 = (size_t)2 * Mpad * 512 / 4;
    cast_x_all<<<(int)((total4 + 255) / 256), 256, 0, stream>>>(x, wtx, xb, N, Mpad);

    // CSR build (independent of GEMM)
    init_deg<<<nb, 256, 0, stream>>>(deg, N2);
    csr_count<<<(2 * E + 255) / 256, 256, 0, stream>>>(adj, wadj, E, N, deg);
    scanA<<<nb, 256, 0, stream>>>(deg, off, bsum, N2);
    scanB<<<1, 256, 0, stream>>>(bsum, bbase, nb, off, N2);
    scanC<<<nb, 256, 0, stream>>>(off, bbase, cursor, csrc, N2);
    csr_scatter<<<(2 * E + 255) / 256, 256, 0, stream>>>(adj, wadj, E, N, cursor, csrc);

    // GEMM over both branches
    dim3 gg(2 * Mpad / 128, 4, 1);
    gemm_bf16<<<gg, 256, 0, stream>>>(xb, Wt, hb);
    att_scores_cast<<<(N2 + 3) / 4, 256, 0, stream>>>(hb, att_s, att_d, asrc, adst, h8, N, Mpad);

    gat_aggregate3<<<2048, 256, 0, stream>>>(h8, asrc, adst, off, csrc, bias, partA, partB,
                                             N, Mpad);

    reduce_partials<<<4, 256, 0, stream>>>(partA, partB, gvec, 1.0f / (float)N);
    fc_final<<<16, 256, 0, stream>>>(gvec, fc1w, fc1b, out);
}